// Round 6
// baseline (905.057 us; speedup 1.0000x reference)
//
#include <hip/hip_runtime.h>
#include <hip/hip_bf16.h>
#include <math.h>

typedef __bf16 bf16_t;
typedef __attribute__((ext_vector_type(8))) __bf16 bf16x8;
typedef __attribute__((ext_vector_type(4))) __bf16 bf16x4;
typedef __attribute__((ext_vector_type(4))) float f32x4;

#define NTOK 8192   // B*T
#define HDIM 1024
#define DFF  4096
#define RHID 512

__device__ __forceinline__ float gelu_exact(float v) {
  return 0.5f * v * (1.0f + erff(v * 0.70710678118654752f));
}

// tanh-form gelu via sigmoid; max abs err ~3e-4 (noise vs bf16 quantization).
__device__ __forceinline__ float gelu_fast(float v) {
  const float g = 1.5957691216057308f * (v + 0.044715f * v * v * v);
  return v / (1.0f + __expf(-g));
}

__device__ __forceinline__ void async_cp16(void* lds, const void* g) {
  __builtin_amdgcn_global_load_lds(
      (__attribute__((address_space(1))) void*)g,
      (__attribute__((address_space(3))) void*)lds, 16, 0, 0);
}

// XCD-aware remap: blocks round-robin XCDs on g&7; each XCD owns an 8-mt
// strip (A-strip L2-resident), mt fastest so B-tiles reused back-to-back.
// Works for 64mt x {32,16,4} nt grids (2048 / 1024 / 256 blocks).
__device__ __forceinline__ void remap_tile(int g, int& mt, int& nt) {
  mt = ((g & 7) << 3) | ((g >> 3) & 7);
  nt = g >> 6;
}

// ---------------------------------------------------------------------------
// GEMM tile, BK=64 single-buffered. 4 waves as 2x2; wave tile (WM*16)x(WN*16);
// block tile (WM*32)x(WN*32). LDS: [row][64k] as 8 slots of 8 elems, rotation
// swizzle slot=(kg+row)&7 -> 2-way banks (free). Row stride 128 B.
// MODE 0: h = bf16(gelu_fast(C)) -> Hout.
// MODE 1: x = C; store hi/lo bf16 split (+ fp32 Xout iff WRITE_OUT).
// MODE 2: x = w*C + (1-w)*(hi+lo); store hi/lo (+ fp32 Xout iff WRITE_OUT).
// ---------------------------------------------------------------------------
template<int MODE, bool WRITE_OUT, int WM, int WN>
__device__ __forceinline__ void body_tile(
    int mt, int nt,
    const bf16_t* __restrict__ A, const bf16_t* __restrict__ Bt,
    const float* __restrict__ bias, int N, int K,
    bf16_t* __restrict__ Hout, float* __restrict__ Xout,
    bf16_t* __restrict__ Xb, bf16_t* __restrict__ Xlo,
    const float* __restrict__ Wmix,
    bf16_t* As, bf16_t* Bs)
{
  constexpr int BM  = WM * 32;
  constexpr int BN  = WN * 32;
  constexpr int ACH = BM / 32;   // 16B staging chunks per thread (A)
  constexpr int BCH = BN / 32;   // (B)
  const int tid  = threadIdx.x;
  const int lane = tid & 63;
  const int wv   = tid >> 6;
  const int wm   = wv >> 1;
  const int wn   = wv & 1;
  const int lr   = lane & 15;
  const int quad = lane >> 4;
  const int m0 = mt * BM;
  const int n0 = nt * BN;

  f32x4 acc[WM][WN];
#pragma unroll
  for (int i = 0; i < WM; ++i)
#pragma unroll
    for (int j = 0; j < WN; ++j)
      acc[i][j] = (f32x4){0.f, 0.f, 0.f, 0.f};

  // staging: chunk c=tid -> row tid>>3, slot tid&7; chunk t adds 32 rows
  // (row&7 unchanged -> same swizzle for all t).
  const int c   = tid;
  const int row = c >> 3;
  const int ks  = (((c & 7) - (row & 7)) & 7) * 8;
  const bf16_t* Agb = A  + (size_t)(m0 + row) * K + ks;
  const bf16_t* Bgb = Bt + (size_t)(n0 + row) * K + ks;
  char* lAb = (char*)As + c * 16;
  char* lBb = (char*)Bs + c * 16;

  for (int kb = 0; kb < K; kb += 64) {
    __syncthreads();
#pragma unroll
    for (int t = 0; t < ACH; ++t)
      async_cp16(lAb + 4096 * t, Agb + (size_t)32 * t * K + kb);
#pragma unroll
    for (int t = 0; t < BCH; ++t)
      async_cp16(lBb + 4096 * t, Bgb + (size_t)32 * t * K + kb);
    __syncthreads();
#pragma unroll
    for (int kk = 0; kk < 2; ++kk) {
      const int kg = kk * 4 + quad;
      bf16x8 af[WM], bfr[WN];
#pragma unroll
      for (int i = 0; i < WM; ++i) {
        const int ra = wm * (WM * 16) + i * 16 + lr;
        af[i] = *(const bf16x8*)&As[ra * 64 + ((kg + ra) & 7) * 8];
      }
#pragma unroll
      for (int j = 0; j < WN; ++j) {
        const int rb = wn * (WN * 16) + j * 16 + lr;
        bfr[j] = *(const bf16x8*)&Bs[rb * 64 + ((kg + rb) & 7) * 8];
      }
#pragma unroll
      for (int i = 0; i < WM; ++i)
#pragma unroll
        for (int j = 0; j < WN; ++j)
          acc[i][j] = __builtin_amdgcn_mfma_f32_16x16x32_bf16(af[i], bfr[j], acc[i][j], 0, 0, 0);
    }
  }

#pragma unroll
  for (int i = 0; i < WM; ++i) {
#pragma unroll
    for (int r = 0; r < 4; ++r) {
      const int gm = m0 + wm * (WM * 16) + i * 16 + quad * 4 + r;
      float wmix = 0.f, onemw = 0.f;
      if (MODE == 2) { wmix = Wmix[gm]; onemw = 1.f - wmix; }
#pragma unroll
      for (int j = 0; j < WN; ++j) {
        const int gn = n0 + wn * (WN * 16) + j * 16 + lr;
        float v = acc[i][j][r] + bias[gn];
        if (MODE == 0) {
          Hout[(size_t)gm * N + gn] = (bf16_t)gelu_fast(v);
        } else {
          const size_t idx = (size_t)gm * N + gn;
          if (MODE == 2) {
            const float xold = (float)Xb[idx] + (float)Xlo[idx];
            v = wmix * v + onemw * xold;
          }
          const bf16_t hi = (bf16_t)v;
          Xb[idx]  = hi;
          Xlo[idx] = (bf16_t)(v - (float)hi);
          if (WRITE_OUT) Xout[idx] = v;
        }
      }
    }
  }
}

// ---------------------------------------------------------------------------
// Router tile (hi/lo split ~fp32), BK=32 single-buffered, 32KB LDS:
// acc = Ah*Bh + Al*Bh + Ah*Bl; out = gelu_exact -> fp32 (halting safety).
// ---------------------------------------------------------------------------
__device__ __forceinline__ void router_tile(
    int mt, int nt,
    const bf16_t* __restrict__ Ah, const bf16_t* __restrict__ Al,
    const bf16_t* __restrict__ Bh, const bf16_t* __restrict__ Bl,
    const float* __restrict__ bias, float* __restrict__ Hr,
    bf16_t* Ahs, bf16_t* Als, bf16_t* Bhs, bf16_t* Bls)
{
  const int K = HDIM, N = RHID;
  const int tid  = threadIdx.x;
  const int lane = tid & 63;
  const int wv   = tid >> 6;
  const int wm   = wv >> 1;
  const int wn   = wv & 1;
  const int lr   = lane & 15;
  const int quad = lane >> 4;
  const int m0 = mt * 128;
  const int n0 = nt * 128;

  f32x4 acc[4][4];
#pragma unroll
  for (int i = 0; i < 4; ++i)
#pragma unroll
    for (int j = 0; j < 4; ++j)
      acc[i][j] = (f32x4){0.f, 0.f, 0.f, 0.f};

  const int c0 = tid;
  const int c1 = tid + 256;
  const int r0 = c0 >> 2, r1 = c1 >> 2;
  const int ks0 = ((c0 ^ r0) & 3) * 8;
  const int ks1 = ((c1 ^ r1) & 3) * 8;
  const size_t aoff0 = (size_t)(m0 + r0) * K + ks0;
  const size_t aoff1 = (size_t)(m0 + r1) * K + ks1;
  const size_t boff0 = (size_t)(n0 + r0) * K + ks0;
  const size_t boff1 = (size_t)(n0 + r1) * K + ks1;
  const int sw = ((quad ^ lr) & 3) * 8;

  for (int k0 = 0; k0 < K; k0 += 32) {
    __syncthreads();
    async_cp16((char*)Ahs + c0 * 16, Ah + aoff0 + k0);
    async_cp16((char*)Ahs + c1 * 16, Ah + aoff1 + k0);
    async_cp16((char*)Als + c0 * 16, Al + aoff0 + k0);
    async_cp16((char*)Als + c1 * 16, Al + aoff1 + k0);
    async_cp16((char*)Bhs + c0 * 16, Bh + boff0 + k0);
    async_cp16((char*)Bhs + c1 * 16, Bh + boff1 + k0);
    async_cp16((char*)Bls + c0 * 16, Bl + boff0 + k0);
    async_cp16((char*)Bls + c1 * 16, Bl + boff1 + k0);
    __syncthreads();
    bf16x8 ah[4], al[4], bh[4], bl[4];
#pragma unroll
    for (int i = 0; i < 4; ++i) {
      const int ao = (wm * 64 + i * 16 + lr) * 32 + sw;
      ah[i] = *(const bf16x8*)&Ahs[ao];
      al[i] = *(const bf16x8*)&Als[ao];
    }
#pragma unroll
    for (int j = 0; j < 4; ++j) {
      const int bo = (wn * 64 + j * 16 + lr) * 32 + sw;
      bh[j] = *(const bf16x8*)&Bhs[bo];
      bl[j] = *(const bf16x8*)&Bls[bo];
    }
#pragma unroll
    for (int i = 0; i < 4; ++i)
#pragma unroll
      for (int j = 0; j < 4; ++j) {
        acc[i][j] = __builtin_amdgcn_mfma_f32_16x16x32_bf16(ah[i], bh[j], acc[i][j], 0, 0, 0);
        acc[i][j] = __builtin_amdgcn_mfma_f32_16x16x32_bf16(al[i], bh[j], acc[i][j], 0, 0, 0);
        acc[i][j] = __builtin_amdgcn_mfma_f32_16x16x32_bf16(ah[i], bl[j], acc[i][j], 0, 0, 0);
      }
  }

#pragma unroll
  for (int i = 0; i < 4; ++i)
#pragma unroll
    for (int r = 0; r < 4; ++r) {
      const int gm = m0 + wm * 64 + i * 16 + quad * 4 + r;
#pragma unroll
      for (int j = 0; j < 4; ++j) {
        const int gn = n0 + wn * 64 + j * 16 + lr;
        Hr[(size_t)gm * N + gn] = gelu_exact(acc[i][j][r] + bias[gn]);
      }
    }
}

// MODE1/MODE2 standalone GEMM: 128x64 tiles -> 1024 blocks (4+/CU resident),
// 24KB LDS. launch_bounds(256,4): min 4 waves/EU = 4 blocks/CU.
template<int MODE, bool WRITE_OUT>
__global__ __launch_bounds__(256, 4)
void k_gemm(const bf16_t* __restrict__ A, const bf16_t* __restrict__ Bt,
            const float* __restrict__ bias, int N, int K,
            float* __restrict__ Xout, bf16_t* __restrict__ Xb,
            bf16_t* __restrict__ Xlo, const float* __restrict__ Wmix)
{
  __shared__ __align__(16) bf16_t sm[12288];  // A 128x64 (16KB) + B 64x64 (8KB)
  int mt, nt;
  remap_tile(blockIdx.x, mt, nt);
  body_tile<MODE, WRITE_OUT, 4, 2>(mt, nt, A, Bt, bias, N, K,
                                   nullptr, Xout, Xb, Xlo, Wmix, sm, sm + 8192);
}

// MODE0 body 128x128 tiles (2048 blocks) + optional fused router tail (256).
// 32KB LDS -> up to 5 resident blocks/CU.
__global__ __launch_bounds__(256, 4)
void k_body0_router(const bf16_t* __restrict__ xb, const bf16_t* __restrict__ W1t,
                    const float* __restrict__ bb1, bf16_t* __restrict__ hbuf,
                    const bf16_t* __restrict__ xlo,
                    const bf16_t* __restrict__ R1h, const bf16_t* __restrict__ R1l,
                    const float* __restrict__ Rb1, float* __restrict__ hr,
                    int nbody)
{
  __shared__ __align__(16) bf16_t sm[16384];  // 32KB
  const int g = blockIdx.x;
  if (g < nbody) {
    int mt, nt;
    remap_tile(g, mt, nt);
    body_tile<0, false, 4, 4>(mt, nt, xb, W1t, bb1, DFF, HDIM, hbuf,
                              nullptr, nullptr, nullptr, nullptr,
                              sm, sm + 8192);
  } else {
    int mt, nt;
    remap_tile(g - nbody, mt, nt);
    router_tile(mt, nt, xb, xlo, R1h, R1l, Rb1, hr,
                sm, sm + 4096, sm + 8192, sm + 12288);
  }
}

// ---------------------------------------------------------------------------
// ACT: one wave per token, fp32 logit + exact halting update.
// ---------------------------------------------------------------------------
__global__ void act_kernel(const float* __restrict__ Hr,
                           const float* __restrict__ rw2, const float* __restrict__ rb2,
                           float* __restrict__ cum_p, float* __restrict__ still_r,
                           float* __restrict__ wsum, float* __restrict__ wvec)
{
  const int t = blockIdx.x * 4 + (threadIdx.x >> 6);
  const int lane = threadIdx.x & 63;
  float s = 0.f;
#pragma unroll
  for (int j = 0; j < 8; ++j) {
    const int m = lane + j * 64;
    s += Hr[(size_t)t * RHID + m] * rw2[m];
  }
  for (int off = 32; off > 0; off >>= 1) s += __shfl_down(s, off, 64);
  if (lane == 0) {
    const float logit = s + rb2[0];
    const float p = 1.f / (1.f + expf(-logit));
    const float cum = cum_p[t];
    const float still = still_r[t];
    const float rem = fmaxf(1.f - cum, 0.f);
    const bool halt = (cum + p) >= 0.99f;
    const float w = (halt ? rem : p) * still;
    wvec[t] = w;
    wsum[t] += w;
    cum_p[t] = cum + w;
    if (halt) still_r[t] = 0.f;
  }
}

// fp32 (R x C) -> bf16 transpose (C x R), optional lo residual output.
__global__ void transpose_to_bf16(const float* __restrict__ src, int srcld, int dstld,
                                  bf16_t* __restrict__ dst, bf16_t* __restrict__ dlo)
{
  __shared__ float tile[32][33];
  const int tx = threadIdx.x & 31;
  const int ty = threadIdx.x >> 5;
  const int bx = blockIdx.x;
  const int by = blockIdx.y;
#pragma unroll
  for (int l = 0; l < 4; ++l)
    tile[ty + l * 8][tx] = src[(size_t)(by * 32 + ty + l * 8) * srcld + bx * 32 + tx];
  __syncthreads();
#pragma unroll
  for (int l = 0; l < 4; ++l) {
    const int c = bx * 32 + ty + l * 8;
    const int r = by * 32 + tx;
    const float v = tile[tx][ty + l * 8];
    const bf16_t hi = (bf16_t)v;
    dst[(size_t)c * dstld + r] = hi;
    if (dlo) dlo[(size_t)c * dstld + r] = (bf16_t)(v - (float)hi);
  }
}

__global__ void cvt_x_kernel(const float4* __restrict__ x, bf16x4* __restrict__ xb, int n4)
{
  const int i = blockIdx.x * 256 + threadIdx.x;
  if (i >= n4) return;
  const float4 v = x[i];
  bf16x4 hb;
  hb[0] = (bf16_t)v.x; hb[1] = (bf16_t)v.y; hb[2] = (bf16_t)v.z; hb[3] = (bf16_t)v.w;
  xb[i] = hb;
}

__global__ void init_state_kernel(float* __restrict__ cum, float* __restrict__ still,
                                  float* __restrict__ wsum)
{
  const int i = blockIdx.x * 256 + threadIdx.x;
  cum[i] = 0.f; still[i] = 1.f; wsum[i] = 1.f;
}

__global__ void finalize_kernel(const float* __restrict__ wsum, float* __restrict__ out)
{
  __shared__ float red[256];
  float s = 0.f;
  for (int i = threadIdx.x; i < NTOK; i += 256) s += wsum[i];
  red[threadIdx.x] = s;
  __syncthreads();
  for (int o = 128; o > 0; o >>= 1) {
    if (threadIdx.x < o) red[threadIdx.x] += red[threadIdx.x + o];
    __syncthreads();
  }
  if (threadIdx.x == 0) {
    const float avg = red[0] / (float)NTOK;
    float d = avg - 2.5f;
    d = fmaxf(d, 0.f);
    out[0] = 0.01f * d * d;
  }
}

extern "C" void kernel_launch(void* const* d_in, const int* in_sizes, int n_in,
                              void* d_out, int out_size, void* d_ws, size_t ws_size,
                              hipStream_t stream) {
  const float* x   = (const float*)d_in[0];
  const float* Wb1 = (const float*)d_in[1];
  const float* bb1 = (const float*)d_in[2];
  const float* Wb2 = (const float*)d_in[3];
  const float* bb2 = (const float*)d_in[4];
  const float* Rw1 = (const float*)d_in[5];  // (3, 1025, 512)
  const float* Rb1 = (const float*)d_in[6];  // (3, 512)
  const float* Rw2 = (const float*)d_in[7];  // (3, 512)
  const float* Rb2 = (const float*)d_in[8];  // (3,)
  float* out = (float*)d_out;

  char* ws = (char*)d_ws;
  size_t off = 0;
  auto carve = [&](size_t bytes) -> void* {
    void* p = ws + off;
    off += (bytes + 255) & ~(size_t)255;
    return p;
  };
  bf16_t* xb   = (bf16_t*)carve((size_t)NTOK * HDIM * 2);
  bf16_t* xlo  = (bf16_t*)carve((size_t)NTOK * HDIM * 2);
  bf16_t* hbuf = (bf16_t*)carve((size_t)NTOK * DFF * 2);
  bf16_t* W1t  = (bf16_t*)carve((size_t)HDIM * DFF * 2);
  bf16_t* W2t  = (bf16_t*)carve((size_t)HDIM * DFF * 2);
  bf16_t* R1h  = (bf16_t*)carve((size_t)3 * RHID * HDIM * 2);
  bf16_t* R1l  = (bf16_t*)carve((size_t)3 * RHID * HDIM * 2);
  float*  hr   = (float*)carve((size_t)NTOK * RHID * 4);
  float*  cum  = (float*)carve((size_t)NTOK * 4);
  float*  stil = (float*)carve((size_t)NTOK * 4);
  float*  wsum = (float*)carve((size_t)NTOK * 4);
  float*  wvec = (float*)carve((size_t)NTOK * 4);

  // weight prep
  transpose_to_bf16<<<dim3(128, 32), 256, 0, stream>>>(Wb1, DFF, HDIM, W1t, nullptr);
  transpose_to_bf16<<<dim3(32, 128), 256, 0, stream>>>(Wb2, HDIM, DFF, W2t, nullptr);
  for (int i = 0; i < 3; ++i)
    transpose_to_bf16<<<dim3(16, 32), 256, 0, stream>>>(
        Rw1 + (size_t)i * 1025 * RHID, RHID, HDIM,
        R1h + (size_t)i * RHID * HDIM, R1l + (size_t)i * RHID * HDIM);
  cvt_x_kernel<<<8192, 256, 0, stream>>>((const float4*)x, (bf16x4*)xb, NTOK * HDIM / 4);
  init_state_kernel<<<32, 256, 0, stream>>>(cum, stil, wsum);

  // mandatory first body: x = body(x); keep x only as hi/lo bf16 pair
  k_body0_router<<<2048, 256, 0, stream>>>(xb, W1t, bb1, hbuf, xlo,
                                           nullptr, nullptr, nullptr, nullptr, 2048);
  k_gemm<1, false><<<1024, 256, 0, stream>>>(hbuf, W2t, bb2, HDIM, DFF,
                                             nullptr, xb, xlo, nullptr);

  for (int i = 0; i < 3; ++i) {
    k_body0_router<<<2048 + 256, 256, 0, stream>>>(
        xb, W1t, bb1, hbuf, xlo,
        R1h + (size_t)i * RHID * HDIM, R1l + (size_t)i * RHID * HDIM,
        Rb1 + (size_t)i * RHID, hr, 2048);
    act_kernel<<<2048, 256, 0, stream>>>(hr, Rw2 + (size_t)i * RHID, Rb2 + i,
                                         cum, stil, wsum, wvec);
    if (i < 2)
      k_gemm<2, false><<<1024, 256, 0, stream>>>(hbuf, W2t, bb2, HDIM, DFF,
                                                 nullptr, xb, xlo, wvec);
    else
      k_gemm<2, true><<<1024, 256, 0, stream>>>(hbuf, W2t, bb2, HDIM, DFF,
                                                out, xb, xlo, wvec);
  }

  finalize_kernel<<<1, 256, 0, stream>>>(wsum, out + (size_t)NTOK * HDIM);
  (void)in_sizes; (void)n_in; (void)out_size; (void)ws_size;
}

// Round 8
// 848.282 us; speedup vs baseline: 1.0669x; 1.0669x over previous
//
#include <hip/hip_runtime.h>
#include <hip/hip_bf16.h>
#include <math.h>

typedef __bf16 bf16_t;
typedef __attribute__((ext_vector_type(8))) __bf16 bf16x8;
typedef __attribute__((ext_vector_type(4))) __bf16 bf16x4;
typedef __attribute__((ext_vector_type(4))) float f32x4;

#define NTOK 8192   // B*T
#define HDIM 1024
#define DFF  4096
#define RHID 512

__device__ __forceinline__ float gelu_exact(float v) {
  return 0.5f * v * (1.0f + erff(v * 0.70710678118654752f));
}

// tanh-form gelu via sigmoid; max abs err ~3e-4 (noise vs bf16 quantization).
__device__ __forceinline__ float gelu_fast(float v) {
  const float g = 1.5957691216057308f * (v + 0.044715f * v * v * v);
  return v / (1.0f + __expf(-g));
}

__device__ __forceinline__ void async_cp16(void* lds, const void* g) {
  __builtin_amdgcn_global_load_lds(
      (__attribute__((address_space(1))) void*)g,
      (__attribute__((address_space(3))) void*)lds, 16, 0, 0);
}

// XCD-aware remap: blocks round-robin XCDs on g&7; each XCD owns an 8-mt
// strip (A-strip L2-resident), mt fastest so B-tiles reused back-to-back.
__device__ __forceinline__ void remap_tile(int g, int& mt, int& nt) {
  mt = ((g & 7) << 3) | ((g >> 3) & 7);
  nt = g >> 6;
}

// ---------------------------------------------------------------------------
// GEMM tile, BK=64 single-buffered (r4-proven loop: sync, stage, sync,
// compute). 4 waves 2x2; wave tile (WM*16)x(WN*16); block (WM*32)x(WN*32).
// LDS: [row][64k] as 8 slots of 8 elems, rotation swizzle slot=(kg+row)&7
// -> 2-way banks (free). Row stride 128 B.
// MODE 0: h = bf16(gelu_fast(C)) -> Hout.
// MODE 1: x = C; hi/lo bf16 split (+ fp32 Xout iff WRITE_OUT).
// MODE 2: x = w*C + (1-w)*(hi+lo); hi/lo (+ fp32 Xout iff WRITE_OUT).
// ---------------------------------------------------------------------------
template<int MODE, bool WRITE_OUT, int WM, int WN>
__device__ __forceinline__ void body_tile(
    int mt, int nt,
    const bf16_t* __restrict__ A, const bf16_t* __restrict__ Bt,
    const float* __restrict__ bias, int N, int K,
    bf16_t* __restrict__ Hout, float* __restrict__ Xout,
    bf16_t* __restrict__ Xb, bf16_t* __restrict__ Xlo,
    const float* __restrict__ Wmix,
    bf16_t* As, bf16_t* Bs)
{
  constexpr int BM  = WM * 32;
  constexpr int BN  = WN * 32;
  constexpr int ACH = BM / 32;
  constexpr int BCH = BN / 32;
  const int tid  = threadIdx.x;
  const int lane = tid & 63;
  const int wv   = tid >> 6;
  const int wm   = wv >> 1;
  const int wn   = wv & 1;
  const int lr   = lane & 15;
  const int quad = lane >> 4;
  const int m0 = mt * BM;
  const int n0 = nt * BN;

  f32x4 acc[WM][WN];
#pragma unroll
  for (int i = 0; i < WM; ++i)
#pragma unroll
    for (int j = 0; j < WN; ++j)
      acc[i][j] = (f32x4){0.f, 0.f, 0.f, 0.f};

  const int c   = tid;
  const int row = c >> 3;
  const int ks  = (((c & 7) - (row & 7)) & 7) * 8;
  const bf16_t* Agb = A  + (size_t)(m0 + row) * K + ks;
  const bf16_t* Bgb = Bt + (size_t)(n0 + row) * K + ks;
  char* lAb = (char*)As + c * 16;
  char* lBb = (char*)Bs + c * 16;

  for (int kb = 0; kb < K; kb += 64) {
    __syncthreads();
#pragma unroll
    for (int t = 0; t < ACH; ++t)
      async_cp16(lAb + 4096 * t, Agb + (size_t)32 * t * K + kb);
#pragma unroll
    for (int t = 0; t < BCH; ++t)
      async_cp16(lBb + 4096 * t, Bgb + (size_t)32 * t * K + kb);
    __syncthreads();
#pragma unroll
    for (int kk = 0; kk < 2; ++kk) {
      const int kg = kk * 4 + quad;
      bf16x8 af[WM], bfr[WN];
#pragma unroll
      for (int i = 0; i < WM; ++i) {
        const int ra = wm * (WM * 16) + i * 16 + lr;
        af[i] = *(const bf16x8*)&As[ra * 64 + ((kg + ra) & 7) * 8];
      }
#pragma unroll
      for (int j = 0; j < WN; ++j) {
        const int rb = wn * (WN * 16) + j * 16 + lr;
        bfr[j] = *(const bf16x8*)&Bs[rb * 64 + ((kg + rb) & 7) * 8];
      }
#pragma unroll
      for (int i = 0; i < WM; ++i)
#pragma unroll
        for (int j = 0; j < WN; ++j)
          acc[i][j] = __builtin_amdgcn_mfma_f32_16x16x32_bf16(af[i], bfr[j], acc[i][j], 0, 0, 0);
    }
  }

#pragma unroll
  for (int i = 0; i < WM; ++i) {
#pragma unroll
    for (int r = 0; r < 4; ++r) {
      const int gm = m0 + wm * (WM * 16) + i * 16 + quad * 4 + r;
      float wmix = 0.f, onemw = 0.f;
      if (MODE == 2) { wmix = Wmix[gm]; onemw = 1.f - wmix; }
#pragma unroll
      for (int j = 0; j < WN; ++j) {
        const int gn = n0 + wn * (WN * 16) + j * 16 + lr;
        float v = acc[i][j][r] + bias[gn];
        if (MODE == 0) {
          Hout[(size_t)gm * N + gn] = (bf16_t)gelu_fast(v);
        } else {
          const size_t idx = (size_t)gm * N + gn;
          if (MODE == 2) {
            const float xold = (float)Xb[idx] + (float)Xlo[idx];
            v = wmix * v + onemw * xold;
          }
          const bf16_t hi = (bf16_t)v;
          Xb[idx]  = hi;
          Xlo[idx] = (bf16_t)(v - (float)hi);
          if (WRITE_OUT) Xout[idx] = v;
        }
      }
    }
  }
}

// ---------------------------------------------------------------------------
// Router tile (hi/lo split ~fp32), BK=32 single-buffered, 32KB LDS:
// acc = Ah*Bh + Al*Bh + Ah*Bl; out = gelu_exact -> fp32 (halting safety).
// ---------------------------------------------------------------------------
__device__ __forceinline__ void router_tile(
    int mt, int nt,
    const bf16_t* __restrict__ Ah, const bf16_t* __restrict__ Al,
    const bf16_t* __restrict__ Bh, const bf16_t* __restrict__ Bl,
    const float* __restrict__ bias, float* __restrict__ Hr,
    bf16_t* Ahs, bf16_t* Als, bf16_t* Bhs, bf16_t* Bls)
{
  const int K = HDIM, N = RHID;
  const int tid  = threadIdx.x;
  const int lane = tid & 63;
  const int wv   = tid >> 6;
  const int wm   = wv >> 1;
  const int wn   = wv & 1;
  const int lr   = lane & 15;
  const int quad = lane >> 4;
  const int m0 = mt * 128;
  const int n0 = nt * 128;

  f32x4 acc[4][4];
#pragma unroll
  for (int i = 0; i < 4; ++i)
#pragma unroll
    for (int j = 0; j < 4; ++j)
      acc[i][j] = (f32x4){0.f, 0.f, 0.f, 0.f};

  const int c0 = tid;
  const int c1 = tid + 256;
  const int r0 = c0 >> 2, r1 = c1 >> 2;
  const int ks0 = ((c0 ^ r0) & 3) * 8;
  const int ks1 = ((c1 ^ r1) & 3) * 8;
  const size_t aoff0 = (size_t)(m0 + r0) * K + ks0;
  const size_t aoff1 = (size_t)(m0 + r1) * K + ks1;
  const size_t boff0 = (size_t)(n0 + r0) * K + ks0;
  const size_t boff1 = (size_t)(n0 + r1) * K + ks1;
  const int sw = ((quad ^ lr) & 3) * 8;

  for (int k0 = 0; k0 < K; k0 += 32) {
    __syncthreads();
    async_cp16((char*)Ahs + c0 * 16, Ah + aoff0 + k0);
    async_cp16((char*)Ahs + c1 * 16, Ah + aoff1 + k0);
    async_cp16((char*)Als + c0 * 16, Al + aoff0 + k0);
    async_cp16((char*)Als + c1 * 16, Al + aoff1 + k0);
    async_cp16((char*)Bhs + c0 * 16, Bh + boff0 + k0);
    async_cp16((char*)Bhs + c1 * 16, Bh + boff1 + k0);
    async_cp16((char*)Bls + c0 * 16, Bl + boff0 + k0);
    async_cp16((char*)Bls + c1 * 16, Bl + boff1 + k0);
    __syncthreads();
    bf16x8 ah[4], al[4], bh[4], bl[4];
#pragma unroll
    for (int i = 0; i < 4; ++i) {
      const int ao = (wm * 64 + i * 16 + lr) * 32 + sw;
      ah[i] = *(const bf16x8*)&Ahs[ao];
      al[i] = *(const bf16x8*)&Als[ao];
    }
#pragma unroll
    for (int j = 0; j < 4; ++j) {
      const int bo = (wn * 64 + j * 16 + lr) * 32 + sw;
      bh[j] = *(const bf16x8*)&Bhs[bo];
      bl[j] = *(const bf16x8*)&Bls[bo];
    }
#pragma unroll
    for (int i = 0; i < 4; ++i)
#pragma unroll
      for (int j = 0; j < 4; ++j) {
        acc[i][j] = __builtin_amdgcn_mfma_f32_16x16x32_bf16(ah[i], bh[j], acc[i][j], 0, 0, 0);
        acc[i][j] = __builtin_amdgcn_mfma_f32_16x16x32_bf16(al[i], bh[j], acc[i][j], 0, 0, 0);
        acc[i][j] = __builtin_amdgcn_mfma_f32_16x16x32_bf16(ah[i], bl[j], acc[i][j], 0, 0, 0);
      }
  }

#pragma unroll
  for (int i = 0; i < 4; ++i)
#pragma unroll
    for (int r = 0; r < 4; ++r) {
      const int gm = m0 + wm * 64 + i * 16 + quad * 4 + r;
#pragma unroll
      for (int j = 0; j < 4; ++j) {
        const int gn = n0 + wn * 64 + j * 16 + lr;
        Hr[(size_t)gm * N + gn] = gelu_exact(acc[i][j][r] + bias[gn]);
      }
    }
}

// MODE1/MODE2 standalone GEMM, 128x128 tiles (512 blocks), 32KB LDS
template<int MODE, bool WRITE_OUT>
__global__ __launch_bounds__(256, 4)
void k_gemm(const bf16_t* __restrict__ A, const bf16_t* __restrict__ Bt,
            const float* __restrict__ bias, int N, int K,
            float* __restrict__ Xout, bf16_t* __restrict__ Xb,
            bf16_t* __restrict__ Xlo, const float* __restrict__ Wmix)
{
  __shared__ __align__(16) bf16_t sm[16384];
  int mt, nt;
  remap_tile(blockIdx.x, mt, nt);
  body_tile<MODE, WRITE_OUT, 4, 4>(mt, nt, A, Bt, bias, N, K,
                                   nullptr, Xout, Xb, Xlo, Wmix, sm, sm + 8192);
}

// MODE0 body 128x128 tiles (2048 blocks) + optional fused router tail (256).
__global__ __launch_bounds__(256, 4)
void k_body0_router(const bf16_t* __restrict__ xb, const bf16_t* __restrict__ W1t,
                    const float* __restrict__ bb1, bf16_t* __restrict__ hbuf,
                    const bf16_t* __restrict__ xlo,
                    const bf16_t* __restrict__ R1h, const bf16_t* __restrict__ R1l,
                    const float* __restrict__ Rb1, float* __restrict__ hr,
                    int nbody)
{
  __shared__ __align__(16) bf16_t sm[16384];
  const int g = blockIdx.x;
  if (g < nbody) {
    int mt, nt;
    remap_tile(g, mt, nt);
    body_tile<0, false, 4, 4>(mt, nt, xb, W1t, bb1, DFF, HDIM, hbuf,
                              nullptr, nullptr, nullptr, nullptr,
                              sm, sm + 8192);
  } else {
    int mt, nt;
    remap_tile(g - nbody, mt, nt);
    router_tile(mt, nt, xb, xlo, R1h, R1l, Rb1, hr,
                sm, sm + 4096, sm + 8192, sm + 12288);
  }
}

// ---------------------------------------------------------------------------
// ACT: one wave per token, fp32 logit + exact halting update (in-place state).
// ---------------------------------------------------------------------------
__global__ void act_kernel(const float* __restrict__ Hr,
                           const float* __restrict__ rw2, const float* __restrict__ rb2,
                           float* __restrict__ cum_p, float* __restrict__ still_r,
                           float* __restrict__ wsum, float* __restrict__ wvec)
{
  const int t = blockIdx.x * 4 + (threadIdx.x >> 6);
  const int lane = threadIdx.x & 63;
  float s = 0.f;
#pragma unroll
  for (int j = 0; j < 8; ++j) {
    const int m = lane + j * 64;
    s += Hr[(size_t)t * RHID + m] * rw2[m];
  }
  for (int off = 32; off > 0; off >>= 1) s += __shfl_down(s, off, 64);
  if (lane == 0) {
    const float logit = s + rb2[0];
    const float p = 1.f / (1.f + expf(-logit));
    const float cum = cum_p[t];
    const float still = still_r[t];
    const float rem = fmaxf(1.f - cum, 0.f);
    const bool halt = (cum + p) >= 0.99f;
    const float w = (halt ? rem : p) * still;
    wvec[t] = w;
    wsum[t] += w;
    cum_p[t] = cum + w;
    if (halt) still_r[t] = 0.f;
  }
}

// ---------------------------------------------------------------------------
// Fused prep: Wb1/Wb2/Rw1 transposes + x->bf16 convert + ACT state init.
// ---------------------------------------------------------------------------
__device__ __forceinline__ void transpose_tile(
    const float* __restrict__ src, int srcld, int dstld,
    bf16_t* __restrict__ dst, bf16_t* __restrict__ dlo,
    int bx, int by, float* tile /* 32x33 */)
{
  const int tx = threadIdx.x & 31;
  const int ty = threadIdx.x >> 5;
#pragma unroll
  for (int l = 0; l < 4; ++l)
    tile[(ty + l * 8) * 33 + tx] = src[(size_t)(by * 32 + ty + l * 8) * srcld + bx * 32 + tx];
  __syncthreads();
#pragma unroll
  for (int l = 0; l < 4; ++l) {
    const int c = bx * 32 + ty + l * 8;
    const int r = by * 32 + tx;
    const float v = tile[tx * 33 + ty + l * 8];
    const bf16_t hi = (bf16_t)v;
    dst[(size_t)c * dstld + r] = hi;
    if (dlo) dlo[(size_t)c * dstld + r] = (bf16_t)(v - (float)hi);
  }
}

__global__ void prep_kernel(const float* __restrict__ x,
                            const float* __restrict__ Wb1,
                            const float* __restrict__ Wb2,
                            const float* __restrict__ Rw1,
                            bf16_t* __restrict__ xb,
                            bf16_t* __restrict__ W1t, bf16_t* __restrict__ W2t,
                            bf16_t* __restrict__ R1h, bf16_t* __restrict__ R1l,
                            float* __restrict__ cum0, float* __restrict__ stil0,
                            float* __restrict__ wsum0)
{
  __shared__ float tile[32 * 33];
  const int g = blockIdx.x;
  if (g < 4096) {                       // Wb1 (H x DFF) -> W1t (DFF x H)
    transpose_tile(Wb1, DFF, HDIM, W1t, nullptr, g & 127, g >> 7, tile);
  } else if (g < 8192) {                // Wb2 (DFF x H) -> W2t (H x DFF)
    const int g2 = g - 4096;
    transpose_tile(Wb2, HDIM, DFF, W2t, nullptr, g2 & 31, g2 >> 5, tile);
  } else if (g < 9728) {                // Rw1[i] (first 1024 of 1025 rows) -> hi/lo
    const int g3 = g - 8192;
    const int i  = g3 >> 9;
    const int r  = g3 & 511;
    transpose_tile(Rw1 + (size_t)i * 1025 * RHID, RHID, HDIM,
                   R1h + (size_t)i * RHID * HDIM, R1l + (size_t)i * RHID * HDIM,
                   r & 15, r >> 4, tile);
  } else if (g < 17920) {               // x fp32 -> xb bf16 (vectorized)
    const int i = (g - 9728) * 256 + threadIdx.x;
    const float4 v = ((const float4*)x)[i];
    bf16x4 hb;
    hb[0] = (bf16_t)v.x; hb[1] = (bf16_t)v.y; hb[2] = (bf16_t)v.z; hb[3] = (bf16_t)v.w;
    ((bf16x4*)xb)[i] = hb;
  } else {                              // ACT state init
    const int t = (g - 17920) * 256 + threadIdx.x;
    cum0[t] = 0.f; stil0[t] = 1.f; wsum0[t] = 1.f;
  }
}

__global__ void finalize_kernel(const float* __restrict__ wsum, float* __restrict__ out)
{
  __shared__ float red[256];
  float s = 0.f;
  for (int i = threadIdx.x; i < NTOK; i += 256) s += wsum[i];
  red[threadIdx.x] = s;
  __syncthreads();
  for (int o = 128; o > 0; o >>= 1) {
    if (threadIdx.x < o) red[threadIdx.x] += red[threadIdx.x + o];
    __syncthreads();
  }
  if (threadIdx.x == 0) {
    const float avg = red[0] / (float)NTOK;
    float d = avg - 2.5f;
    d = fmaxf(d, 0.f);
    out[0] = 0.01f * d * d;
  }
}

extern "C" void kernel_launch(void* const* d_in, const int* in_sizes, int n_in,
                              void* d_out, int out_size, void* d_ws, size_t ws_size,
                              hipStream_t stream) {
  const float* x   = (const float*)d_in[0];
  const float* Wb1 = (const float*)d_in[1];
  const float* bb1 = (const float*)d_in[2];
  const float* Wb2 = (const float*)d_in[3];
  const float* bb2 = (const float*)d_in[4];
  const float* Rw1 = (const float*)d_in[5];  // (3, 1025, 512)
  const float* Rb1 = (const float*)d_in[6];  // (3, 512)
  const float* Rw2 = (const float*)d_in[7];  // (3, 512)
  const float* Rb2 = (const float*)d_in[8];  // (3,)
  float* out = (float*)d_out;

  char* ws = (char*)d_ws;
  size_t off = 0;
  auto carve = [&](size_t bytes) -> void* {
    void* p = ws + off;
    off += (bytes + 255) & ~(size_t)255;
    return p;
  };
  bf16_t* xb   = (bf16_t*)carve((size_t)NTOK * HDIM * 2);
  bf16_t* xlo  = (bf16_t*)carve((size_t)NTOK * HDIM * 2);
  bf16_t* hbuf = (bf16_t*)carve((size_t)NTOK * DFF * 2);
  bf16_t* W1t  = (bf16_t*)carve((size_t)HDIM * DFF * 2);
  bf16_t* W2t  = (bf16_t*)carve((size_t)HDIM * DFF * 2);
  bf16_t* R1h  = (bf16_t*)carve((size_t)3 * RHID * HDIM * 2);
  bf16_t* R1l  = (bf16_t*)carve((size_t)3 * RHID * HDIM * 2);
  float*  hr   = (float*)carve((size_t)NTOK * RHID * 4);
  float*  cum  = (float*)carve((size_t)NTOK * 4);
  float*  stil = (float*)carve((size_t)NTOK * 4);
  float*  wsum = (float*)carve((size_t)NTOK * 4);
  float*  wvec = (float*)carve((size_t)NTOK * 4);

  prep_kernel<<<17952, 256, 0, stream>>>(x, Wb1, Wb2, Rw1, xb, W1t, W2t,
                                         R1h, R1l, cum, stil, wsum);

  // mandatory first body: x = body(x); x kept as hi/lo bf16 pair
  k_body0_router<<<2048, 256, 0, stream>>>(xb, W1t, bb1, hbuf, xlo,
                                           nullptr, nullptr, nullptr, nullptr, 2048);
  k_gemm<1, false><<<512, 256, 0, stream>>>(hbuf, W2t, bb2, HDIM, DFF,
                                            nullptr, xb, xlo, nullptr);

  for (int i = 0; i < 3; ++i) {
    k_body0_router<<<2048 + 256, 256, 0, stream>>>(
        xb, W1t, bb1, hbuf, xlo,
        R1h + (size_t)i * RHID * HDIM, R1l + (size_t)i * RHID * HDIM,
        Rb1 + (size_t)i * RHID, hr, 2048);
    act_kernel<<<2048, 256, 0, stream>>>(hr, Rw2 + (size_t)i * RHID, Rb2 + i,
                                         cum, stil, wsum, wvec);
    if (i < 2)
      k_gemm<2, false><<<512, 256, 0, stream>>>(hbuf, W2t, bb2, HDIM, DFF,
                                                nullptr, xb, xlo, wvec);
    else
      k_gemm<2, true><<<512, 256, 0, stream>>>(hbuf, W2t, bb2, HDIM, DFF,
                                               out, xb, xlo, wvec);
  }

  finalize_kernel<<<1, 256, 0, stream>>>(wsum, out + (size_t)NTOK * HDIM);
  (void)in_sizes; (void)n_in; (void)out_size; (void)ws_size;
}